// Round 7
// baseline (564.362 us; speedup 1.0000x reference)
//
#include <hip/hip_runtime.h>
#include <hip/hip_bf16.h>

// Problem constants (fixed by the reference)
#define B_ 8
#define NHID_ 512
#define L_ 2048
#define AL_ 4
#define NHEAD_ 8
#define HDIM_ 64
#define D_ 512
#define SCALE_ 0.125f

typedef unsigned short ushort_t;
typedef __attribute__((ext_vector_type(8))) short bf16x8;
typedef __attribute__((ext_vector_type(8))) unsigned short u16x8;
typedef __attribute__((ext_vector_type(4))) float f32x4;

__device__ __forceinline__ float bf2f(ushort_t u) {
  union { unsigned i; float f; } x; x.i = ((unsigned)u) << 16; return x.f;
}
__device__ __forceinline__ ushort_t f2bf(float f) {   // round-to-nearest-even
  unsigned u = __float_as_uint(f);
  unsigned r = (u + 0x7FFFu + ((u >> 16) & 1u)) >> 16;
  return (ushort_t)r;
}
__device__ __forceinline__ void gload16(const ushort_t* g, ushort_t* l) {
  __builtin_amdgcn_global_load_lds(
      (const __attribute__((address_space(1))) unsigned int*)g,
      (__attribute__((address_space(3))) unsigned int*)l, 16, 0, 0);
}

// ---------------------------------------------------------------------------
// Tiled transpose + convert-to-bf16 (weights only: 512x512, tiny).
// ---------------------------------------------------------------------------
__global__ __launch_bounds__(256)
void transpose_conv(const float* __restrict__ in, ushort_t* __restrict__ out,
                    int R, int C) {
  __shared__ float t[32][33];
  const size_t z = (size_t)blockIdx.z * R * C;
  const int cb = blockIdx.x * 32, rb = blockIdx.y * 32;
  const int tx = threadIdx.x, ty = threadIdx.y;
#pragma unroll
  for (int i = 0; i < 4; i++) {
    const int r = rb + ty + i * 8;
    t[ty + i * 8][tx] = in[z + (size_t)r * C + cb + tx];
  }
  __syncthreads();
#pragma unroll
  for (int i = 0; i < 4; i++) {
    const int c = cb + ty + i * 8;
    out[z + (size_t)c * R + rb + tx] = f2bf(t[tx][ty + i * 8]);
  }
}

__global__ void prep_bias(const float* __restrict__ bq, const float* __restrict__ bk,
                          const float* __restrict__ bv, float* __restrict__ bcat) {
  const int i = blockIdx.x * 256 + threadIdx.x;  // 1536
  const float* s = i < 512 ? bq : (i < 1024 ? bk : bv);
  bcat[i] = s[i & 511];
}

// ---------------------------------------------------------------------------
// bf16 MFMA GEMM, A streamed from native [z][K=512][M] fp32 layout:
//   C[z][n][m] = sum_k A[z][k][m] * Wt[n][k] + bias[n]
//   Wt: [Ntot][512] bf16 (pre-transposed weights, k-contiguous rows)
//   C : routed to C0/C1/C2 by n>>9; each [z][512][M], m-contiguous.
// Tile 128x128, BK=32, 4 waves, 4x4 16x16x32 fragments.
// A staging: reg-staged (16 coalesced dword loads/thread -> RNE bf16 ->
//   ds_write_b128) into XOR-chunk-swizzled LDS (store perm == read perm,
//   oct^((m>>1)&3)); W staging: global_load_lds 16B (linear dest + pre-
//   swizzled source).  2-phase double-buffer (T3-minimum): prefetch k-step
//   t+1 before MFMA of t; ONE barrier per k-step.
// ---------------------------------------------------------------------------
template <int OUTF>
__global__ __launch_bounds__(256)
void gemm_fa(const float* __restrict__ A, const ushort_t* __restrict__ W,
             const float* __restrict__ bias, void* __restrict__ C0,
             void* __restrict__ C1, void* __restrict__ C2,
             int M, long long sA, long long sC, int Ntiles) {
  __shared__ ushort_t lds[16384];  // 32 KB: buf c at c*8192: A [0,4096), W [4096,8192)
  const int tid = threadIdx.x;
  const int l = tid & 63, w = tid >> 6;

  // bijective XCD swizzle (gridDim.x % 8 == 0 for all launches here)
  const int nwg = gridDim.x;
  const int id = (blockIdx.x & 7) * (nwg >> 3) + (blockIdx.x >> 3);
  const int nt = id % Ntiles, mt = id / Ntiles;
  const int bm = mt * 128, bn = nt * 128;
  const float* Ab = A + (size_t)blockIdx.z * sA + bm;

  // A reg-staging: units u = tid, tid+256; m = u&127, k-octet = u>>7
  const int am = tid & 127;
  const int ao0 = tid >> 7, ao1 = (tid >> 7) + 2;
  const int awr0 = am * 32 + ((ao0 ^ ((am >> 1) & 3)) * 8);  // LDS elem offsets
  const int awr1 = am * 32 + ((ao1 ^ ((am >> 1) & 3)) * 8);

  // W staging: chunks cw = j*256 + w*64 + l (j=0,1); dest elems 4096+...
  const ushort_t* wsrc[2];
  int wdoff[2];
#pragma unroll
  for (int j = 0; j < 2; j++) {
    const int cw = j * 256 + w * 64 + l;
    const int row = cw >> 2;
    const int cp = (cw & 3) ^ ((row >> 1) & 3);
    wsrc[j] = W + (size_t)(bn + row) * 512 + cp * 8;
    wdoff[j] = 4096 + j * 2048 + w * 512;  // wave-uniform; HW adds lane*8 elems
  }

  // fragment read offsets (within a buffer): data-tile at 0, W-tile at +4096
  const int wm = (w & 1) * 64, wn = (w >> 1) * 64;
  int boff[4], aoff[4];
#pragma unroll
  for (int i = 0; i < 4; i++) {
    const int rb = wm + i * 16 + (l & 15);
    boff[i] = rb * 32 + (((l >> 4) ^ ((rb >> 1) & 3)) * 8);
    const int ra = wn + i * 16 + (l & 15);
    aoff[i] = 4096 + ra * 32 + (((l >> 4) ^ ((ra >> 1) & 3)) * 8);
  }

  float fa0[8], fa1[8];
#define LOAD_A(kt)                                                        \
  {                                                                       \
    const float* s0_ = Ab + (size_t)((kt) * 32 + ao0 * 8) * M + am;       \
    const float* s1_ = Ab + (size_t)((kt) * 32 + ao1 * 8) * M + am;       \
    _Pragma("unroll") for (int j = 0; j < 8; j++) {                       \
      fa0[j] = s0_[(size_t)j * M];                                        \
      fa1[j] = s1_[(size_t)j * M];                                        \
    }                                                                     \
  }
#define LOAD_W(kt, buf)                                                   \
  {                                                                       \
    _Pragma("unroll") for (int j = 0; j < 2; j++)                         \
        gload16(wsrc[j] + (kt) * 32, &lds[(buf) * 8192 + wdoff[j]]);      \
  }
#define WRITE_A(buf)                                                      \
  {                                                                       \
    bf16x8 p0_, p1_;                                                      \
    _Pragma("unroll") for (int j = 0; j < 8; j++) {                       \
      p0_[j] = (short)f2bf(fa0[j]);                                       \
      p1_[j] = (short)f2bf(fa1[j]);                                       \
    }                                                                     \
    *(bf16x8*)&lds[(buf) * 8192 + awr0] = p0_;                            \
    *(bf16x8*)&lds[(buf) * 8192 + awr1] = p1_;                            \
  }

  // prologue: stage k-step 0 into buf 0
  LOAD_A(0);
  LOAD_W(0, 0);
  WRITE_A(0);
  __syncthreads();

  f32x4 acc[4][4] = {};
  int cur = 0;
  for (int kt = 0; kt < 16; kt++) {
    if (kt < 15) {           // prefetch next k-step into the other buffer
      LOAD_A(kt + 1);
      LOAD_W(kt + 1, cur ^ 1);
    }
    const int cb = cur * 8192;
    bf16x8 bf[4], af[4];
#pragma unroll
    for (int i = 0; i < 4; i++) bf[i] = *(const bf16x8*)&lds[cb + boff[i]];
#pragma unroll
    for (int i = 0; i < 4; i++) af[i] = *(const bf16x8*)&lds[cb + aoff[i]];
#pragma unroll
    for (int ni = 0; ni < 4; ni++)
#pragma unroll
      for (int mi = 0; mi < 4; mi++)
        acc[ni][mi] = __builtin_amdgcn_mfma_f32_16x16x32_bf16(af[ni], bf[mi],
                                                              acc[ni][mi], 0, 0, 0);
    if (kt < 15) WRITE_A(cur ^ 1);  // write prefetched A (no conflict with cur reads)
    __syncthreads();  // readers of cur done + nxt (ds_write & W-DMA) complete
    cur ^= 1;
  }

  // epilogue: D lane map col(m)=l&15, row(n)=(l>>4)*4+r  [m89-verified]
  const int bufi = bn >> 9;
  void* Cb = bufi == 0 ? C0 : (bufi == 1 ? C1 : C2);
  const int nb = bn & 511;
#pragma unroll
  for (int ni = 0; ni < 4; ni++) {
#pragma unroll
    for (int r = 0; r < 4; r++) {
      const int tn = wn + ni * 16 + (l >> 4) * 4 + r;
      const float bv = bias[bn + tn];
      const int nl = nb + tn;
#pragma unroll
      for (int mi = 0; mi < 4; mi++) {
        const int m = bm + wm + mi * 16 + (l & 15);
        const size_t idx = (size_t)blockIdx.z * sC + (size_t)nl * M + m;
        const float val = acc[ni][mi][r] + bv;
        if (OUTF) ((float*)Cb)[idx] = val;
        else      ((ushort_t*)Cb)[idx] = f2bf(val);
      }
    }
  }
#undef LOAD_A
#undef LOAD_W
#undef WRITE_A
}

// ---------------------------------------------------------------------------
// Fused window attention (structure verified in R5; now writes fp32 att).
//   q/k/v: [B][512][L] bf16;  ak/av: [BCH][512][AL*L] bf16;  att: [B][512][L] f32.
// ---------------------------------------------------------------------------
__global__ __launch_bounds__(256)
void attn_win(const ushort_t* __restrict__ q, const ushort_t* __restrict__ k,
              const ushort_t* __restrict__ v, const ushort_t* __restrict__ ak,
              const ushort_t* __restrict__ av, float* __restrict__ att,
              int b0) {
  const int lane = threadIdx.x & 63;
  const int w    = threadIdx.x >> 6;
  const int dc   = lane & 3;
  const int lc   = lane >> 2;
  const int bb = blockIdx.y >> 3, n = blockIdx.y & 7;
  const int b = b0 + bb;
  const int l8 = blockIdx.x * 512 + w * 128 + lc * 8;
  const int d0 = dc * 16;

  const size_t rq = ((size_t)b * D_ + n * HDIM_ + d0) * L_ + l8;
  const size_t ra = ((size_t)bb * D_ + n * HDIM_ + d0) * (size_t)(AL_ * L_) + l8;
  const ushort_t* qp = q + rq;
  const ushort_t* kp = k + rq;
  const ushort_t* vp = v + rq;
  float*          op = att + rq;
  const ushort_t* akp = ak + ra;
  const ushort_t* avp = av + ra;

  float s0[8] = {}, s1[8] = {}, s2[8] = {}, s3[8] = {};
  float s4[8] = {}, s5[8] = {}, s6[8] = {};

#pragma unroll 4
  for (int i = 0; i < 16; ++i) {
    const ushort_t* kr = kp + (size_t)i * L_;
    const ushort_t* ar = akp + (size_t)i * (AL_ * L_);
    const u16x8 qv = *(const u16x8*)(qp + (size_t)i * L_);
    const u16x8 kv = *(const u16x8*)kr;
    const u16x8 a0 = *(const u16x8*)(ar);
    const u16x8 a1 = *(const u16x8*)(ar + L_);
    const u16x8 a2 = *(const u16x8*)(ar + 2 * L_);
    const u16x8 a3 = *(const u16x8*)(ar + 3 * L_);
    float qf[8], kf[8];
#pragma unroll
    for (int j = 0; j < 8; ++j) { qf[j] = bf2f(qv[j]); kf[j] = bf2f(kv[j]); }
    float kl = __shfl_up(kf[7], 4);
    if (lc == 0) kl = (l8 > 0) ? bf2f(kr[-1]) : 0.f;
    float kh = __shfl_down(kf[0], 4);
    if (lc == 15) kh = (l8 + 8 < L_) ? bf2f(kr[8]) : 0.f;
#pragma unroll
    for (int j = 0; j < 8; ++j) {
      s0[j] = fmaf(qf[j], j ? kf[j - 1] : kl, s0[j]);
      s1[j] = fmaf(qf[j], kf[j], s1[j]);
      s2[j] = fmaf(qf[j], j < 7 ? kf[j + 1] : kh, s2[j]);
      s3[j] = fmaf(qf[j], bf2f(a0[j]), s3[j]);
      s4[j] = fmaf(qf[j], bf2f(a1[j]), s4[j]);
      s5[j] = fmaf(qf[j], bf2f(a2[j]), s5[j]);
      s6[j] = fmaf(qf[j], bf2f(a3[j]), s6[j]);
    }
  }

#pragma unroll
  for (int j = 0; j < 8; ++j) {
    s0[j] += __shfl_xor(s0[j], 1); s0[j] += __shfl_xor(s0[j], 2);
    s1[j] += __shfl_xor(s1[j], 1); s1[j] += __shfl_xor(s1[j], 2);
    s2[j] += __shfl_xor(s2[j], 1); s2[j] += __shfl_xor(s2[j], 2);
    s3[j] += __shfl_xor(s3[j], 1); s3[j] += __shfl_xor(s3[j], 2);
    s4[j] += __shfl_xor(s4[j], 1); s4[j] += __shfl_xor(s4[j], 2);
    s5[j] += __shfl_xor(s5[j], 1); s5[j] += __shfl_xor(s5[j], 2);
    s6[j] += __shfl_xor(s6[j], 1); s6[j] += __shfl_xor(s6[j], 2);
  }

#pragma unroll
  for (int j = 0; j < 8; ++j) {
    const float t0 = s0[j] * SCALE_, t1 = s1[j] * SCALE_, t2 = s2[j] * SCALE_;
    const float t3 = s3[j] * SCALE_, t4 = s4[j] * SCALE_, t5 = s5[j] * SCALE_;
    const float t6 = s6[j] * SCALE_;
    const float mx = fmaxf(fmaxf(fmaxf(t0, t1), fmaxf(t2, t3)),
                           fmaxf(fmaxf(t4, t5), t6));
    float e0 = __expf(t0 - mx), e1 = __expf(t1 - mx), e2 = __expf(t2 - mx);
    float e3 = __expf(t3 - mx), e4 = __expf(t4 - mx), e5 = __expf(t5 - mx);
    float e6 = __expf(t6 - mx);
    const float inv = 1.f / (e0 + e1 + e2 + e3 + e4 + e5 + e6);
    s0[j] = e0 * inv; s1[j] = e1 * inv; s2[j] = e2 * inv; s3[j] = e3 * inv;
    s4[j] = e4 * inv; s5[j] = e5 * inv; s6[j] = e6 * inv;
  }

#pragma unroll 4
  for (int i = 0; i < 16; ++i) {
    const ushort_t* vr = vp + (size_t)i * L_;
    const ushort_t* ar = avp + (size_t)i * (AL_ * L_);
    const u16x8 vv = *(const u16x8*)vr;
    const u16x8 a0 = *(const u16x8*)(ar);
    const u16x8 a1 = *(const u16x8*)(ar + L_);
    const u16x8 a2 = *(const u16x8*)(ar + 2 * L_);
    const u16x8 a3 = *(const u16x8*)(ar + 3 * L_);
    float vf[8];
#pragma unroll
    for (int j = 0; j < 8; ++j) vf[j] = bf2f(vv[j]);
    float vl = __shfl_up(vf[7], 4);
    if (lc == 0) vl = (l8 > 0) ? bf2f(vr[-1]) : 0.f;
    float vh = __shfl_down(vf[0], 4);
    if (lc == 15) vh = (l8 + 8 < L_) ? bf2f(vr[8]) : 0.f;
    f32x4 olo, ohi;
#pragma unroll
    for (int j = 0; j < 8; ++j) {
      float r = s0[j] * (j ? vf[j - 1] : vl)
              + s1[j] * vf[j]
              + s2[j] * (j < 7 ? vf[j + 1] : vh);
      r = fmaf(s3[j], bf2f(a0[j]), r);
      r = fmaf(s4[j], bf2f(a1[j]), r);
      r = fmaf(s5[j], bf2f(a2[j]), r);
      r = fmaf(s6[j], bf2f(a3[j]), r);
      if (j < 4) olo[j] = r; else ohi[j - 4] = r;
    }
    *(f32x4*)(op + (size_t)i * L_) = olo;
    *(f32x4*)(op + (size_t)i * L_ + 4) = ohi;
  }
}

// ---------------------------------------------------------------------------
extern "C" void kernel_launch(void* const* d_in, const int* in_sizes, int n_in,
                              void* d_out, int out_size, void* d_ws, size_t ws_size,
                              hipStream_t stream) {
  const float* x  = (const float*)d_in[0];
  const float* ax = (const float*)d_in[1];
  const float* Wq = (const float*)d_in[2];
  const float* bq = (const float*)d_in[3];
  const float* Wk = (const float*)d_in[4];
  const float* bk = (const float*)d_in[5];
  const float* Wv = (const float*)d_in[6];
  const float* bv = (const float*)d_in[7];
  const float* Wo = (const float*)d_in[8];
  const float* bo = (const float*)d_in[9];
  float* out = (float*)d_out;

  // ---- workspace (ushort slots), deterministic batch-chunking ----
  const size_t E   = (size_t)B_ * D_ * L_;        // 8,388,608
  const size_t CH1 = (size_t)D_ * AL_ * L_;       // per-batch ak/av elems
  const size_t wfix = 1536 * 512 + 512 * 512 + 3072;

  // need: qkv (3E bf16) + attf (E fp32 = 2E slots) + 2*BCH*CH1 bf16 + wfix
  int BCH = 8;
  while (BCH > 1 && (5 * E + 2 * (size_t)BCH * CH1 + wfix) * 2 > ws_size)
    BCH >>= 1;
  const size_t chunkE = (size_t)BCH * CH1;

  ushort_t* wsu = (ushort_t*)d_ws;
  ushort_t* qb    = wsu;              // [B][512][L] bf16
  ushort_t* kb    = qb + E;
  ushort_t* vb    = kb + E;
  float*    attf  = (float*)(vb + E); // [B][512][L] fp32 (2E slots)
  ushort_t* akb   = vb + E + 2 * E;   // [BCH][512][AL*L] bf16
  ushort_t* avb   = akb + chunkE;
  ushort_t* WcatT = avb + chunkE;     // [1536][512] bf16
  ushort_t* WoT   = WcatT + 1536 * 512;
  float*    bcat  = (float*)(WoT + 512 * 512);  // [1536] f32

  const dim3 t32x8(32, 8);

  // --- weight prep (tiny) ---
  transpose_conv<<<dim3(16, 16, 1), t32x8, 0, stream>>>(Wq, WcatT, 512, 512);
  transpose_conv<<<dim3(16, 16, 1), t32x8, 0, stream>>>(Wk, WcatT + 512 * 512, 512, 512);
  transpose_conv<<<dim3(16, 16, 1), t32x8, 0, stream>>>(Wv, WcatT + 1024 * 512, 512, 512);
  transpose_conv<<<dim3(16, 16, 1), t32x8, 0, stream>>>(Wo, WoT, 512, 512);
  prep_bias<<<dim3(6), dim3(256), 0, stream>>>(bq, bk, bv, bcat);

  // --- fused q/k/v GEMM from native x: per-batch M=2048, Ntot=1536 ---
  gemm_fa<0><<<dim3(16 * 12, 1, B_), dim3(256), 0, stream>>>(
      x, WcatT, bcat, qb, kb, vb,
      L_, (long long)NHID_ * L_, (long long)D_ * L_, 12);

  // --- ak/av GEMM from native ax + attention, chunked over batches ---
  for (int b0 = 0; b0 < B_; b0 += BCH) {
    const float* axc = ax + (size_t)b0 * NHID_ * AL_ * L_;
    gemm_fa<0><<<dim3(64 * 8, 1, BCH), dim3(256), 0, stream>>>(
        axc, WcatT + 512 * 512, bcat + 512, akb, avb, nullptr,
        AL_ * L_, (long long)NHID_ * AL_ * L_, (long long)CH1, 8);
    attn_win<<<dim3(L_ / 512, BCH * NHEAD_), dim3(256), 0, stream>>>(
        qb, kb, vb, akb, avb, attf, b0);
  }

  // --- output projection from native fp32 att: per-batch M=2048, N=512 ---
  gemm_fa<1><<<dim3(16 * 4, 1, B_), dim3(256), 0, stream>>>(
      attf, WoT, bo, out, nullptr, nullptr,
      L_, (long long)D_ * L_, (long long)NHID_ * L_, 4);
}

// Round 9
// 478.695 us; speedup vs baseline: 1.1790x; 1.1790x over previous
//
#include <hip/hip_runtime.h>
#include <hip/hip_bf16.h>

// Problem constants (fixed by the reference)
#define B_ 8
#define NHID_ 512
#define L_ 2048
#define AL_ 4
#define NHEAD_ 8
#define HDIM_ 64
#define D_ 512
#define SCALE_ 0.125f

typedef unsigned short ushort_t;
typedef __attribute__((ext_vector_type(8))) short bf16x8;
typedef __attribute__((ext_vector_type(8))) unsigned short u16x8;
typedef __attribute__((ext_vector_type(4))) unsigned short u16x4;
typedef __attribute__((ext_vector_type(4))) float f32x4;

__device__ __forceinline__ float bf2f(ushort_t u) {
  union { unsigned i; float f; } x; x.i = ((unsigned)u) << 16; return x.f;
}
__device__ __forceinline__ ushort_t f2bf(float f) {   // round-to-nearest-even
  unsigned u = __float_as_uint(f);
  unsigned r = (u + 0x7FFFu + ((u >> 16) & 1u)) >> 16;
  return (ushort_t)r;
}
__device__ __forceinline__ void gload16(const ushort_t* g, ushort_t* l) {
  __builtin_amdgcn_global_load_lds(
      (const __attribute__((address_space(1))) unsigned int*)g,
      (__attribute__((address_space(3))) unsigned int*)l, 16, 0, 0);
}

// ---------------------------------------------------------------------------
// Fused weight prep (ONE launch): transpose Wq/Wk/Wv -> WcatT, Wo -> WoT
// (all 512x512, 32x32 tiles, grid.x = 4*256 + 1), block 1024 builds bcat.
// ---------------------------------------------------------------------------
__global__ __launch_bounds__(256)
void wprep(const float* __restrict__ Wq, const float* __restrict__ Wk,
           const float* __restrict__ Wv, const float* __restrict__ Wo,
           const float* __restrict__ bq, const float* __restrict__ bk,
           const float* __restrict__ bv, ushort_t* __restrict__ WcatT,
           ushort_t* __restrict__ WoT, float* __restrict__ bcat) {
  const int bid = blockIdx.x;
  const int tx = threadIdx.x, ty = threadIdx.y;
  if (bid == 1024) {  // bias concat
    const int t = ty * 32 + tx;
    for (int i = t; i < 1536; i += 256) {
      const float* s = i < 512 ? bq : (i < 1024 ? bk : bv);
      bcat[i] = s[i & 511];
    }
    return;
  }
  __shared__ float tl[32][33];
  const int wi = bid >> 8;  // 0..3
  const float* src = wi == 0 ? Wq : wi == 1 ? Wk : wi == 2 ? Wv : Wo;
  ushort_t* dst = wi == 0 ? WcatT : wi == 1 ? WcatT + 512 * 512
                : wi == 2 ? WcatT + 1024 * 512 : WoT;
  const int r = bid & 255;
  const int cb = (r & 15) * 32, rb = (r >> 4) * 32;
#pragma unroll
  for (int i = 0; i < 4; i++)
    tl[ty + i * 8][tx] = src[(size_t)(rb + ty + i * 8) * 512 + cb + tx];
  __syncthreads();
#pragma unroll
  for (int i = 0; i < 4; i++)
    dst[(size_t)(cb + ty + i * 8) * 512 + rb + tx] = f2bf(tl[tx][ty + i * 8]);
}

// ---------------------------------------------------------------------------
// Vectorized 64x64 transpose+convert, fp32 in -> bf16 out.
// ONE launch covers BOTH x ([8][512][2048]) and ax ([8][512][8192]).
// out[z][C][R=512]. float4 loads (16B/lane), ushort4 stores (8B/lane).
// ---------------------------------------------------------------------------
__global__ __launch_bounds__(256)
void trans64_in(const float* __restrict__ x, ushort_t* __restrict__ xT,
                const float* __restrict__ ax, ushort_t* __restrict__ axT) {
  __shared__ ushort_t tl[64][68];
  int id = blockIdx.x;
  const float* in; ushort_t* out; int C, z, rt, ct;
  if (id < 2048) {            // x: 8 z * (8 rt * 32 ct)
    in = x; out = xT; C = 2048;
    z = id >> 8; const int r = id & 255; ct = r & 31; rt = r >> 5;
  } else {                    // ax: 8 z * (8 rt * 128 ct)
    id -= 2048;
    in = ax; out = axT; C = 8192;
    z = id >> 10; const int r = id & 1023; ct = r & 127; rt = r >> 7;
  }
  const int rb = rt * 64, cb = ct * 64;
  const int t = threadIdx.x;
  const int cx = t & 15, ry = t >> 4;
#pragma unroll
  for (int i = 0; i < 4; i++) {
    const int rl = ry + i * 16;
    const float4 v = *(const float4*)&in[((size_t)z * 512 + rb + rl) * C + cb + cx * 4];
    u16x4 u; u[0] = f2bf(v.x); u[1] = f2bf(v.y); u[2] = f2bf(v.z); u[3] = f2bf(v.w);
    *(u16x4*)&tl[rl][cx * 4] = u;
  }
  __syncthreads();
  const int rx = t & 15, cy = t >> 4;
#pragma unroll
  for (int i = 0; i < 4; i++) {
    const int cl = cy + i * 16;
    u16x4 u;
#pragma unroll
    for (int j = 0; j < 4; j++) u[j] = tl[rx * 4 + j][cl];
    *(u16x4*)&out[((size_t)z * C + cb + cl) * 512 + rb + rx * 4] = u;
  }
}

// Same 64x64 transpose for bf16 input (att -> attT). C=2048 fixed.
__global__ __launch_bounds__(256)
void trans64_bf(const ushort_t* __restrict__ in, ushort_t* __restrict__ out) {
  __shared__ ushort_t tl[64][68];
  const int id = blockIdx.x;           // 8 z * (8 rt * 32 ct) = 2048
  const int z = id >> 8; const int r = id & 255;
  const int ct = r & 31, rt = r >> 5;
  const int rb = rt * 64, cb = ct * 64;
  const int t = threadIdx.x;
  const int cx = t & 15, ry = t >> 4;
#pragma unroll
  for (int i = 0; i < 4; i++) {
    const int rl = ry + i * 16;
    const u16x4 v = *(const u16x4*)&in[((size_t)z * 512 + rb + rl) * 2048 + cb + cx * 4];
    *(u16x4*)&tl[rl][cx * 4] = v;
  }
  __syncthreads();
  const int rx = t & 15, cy = t >> 4;
#pragma unroll
  for (int i = 0; i < 4; i++) {
    const int cl = cy + i * 16;
    u16x4 u;
#pragma unroll
    for (int j = 0; j < 4; j++) u[j] = tl[rx * 4 + j][cl];
    *(u16x4*)&out[((size_t)z * 2048 + cb + cl) * 512 + rb + rx * 4] = u;
  }
}

// ---------------------------------------------------------------------------
// bf16 MFMA GEMM, DUAL-problem dispatch (body identical to the verified R5
// gemm_mfma; only parameter selection added).
//   C[b][n][m] = sum_k A[(b,m)][k] * Wt[n][k] + bias[n]
//   A : [Mtot][512] bf16 k-contiguous; Wt: [Ntot][512] bf16; C routed by n>>9.
// Tile 128x128, BK=32, 4 waves, 4x4 16x16x32 frags; global_load_lds(16B),
// XOR chunk swizzle c^((row>>1)&3) both sides (rule #21).
// Flat swizzled id < tiles0 -> problem 0, else problem 1.
// ---------------------------------------------------------------------------
template <int OUTF>
__global__ __launch_bounds__(256)
void gemm_dual(const ushort_t* __restrict__ A0, const ushort_t* __restrict__ W0,
               const float* __restrict__ bias0, void* C00, void* C01, void* C02,
               int Nt0, int Ms0, int tiles0,
               const ushort_t* __restrict__ A1, const ushort_t* __restrict__ W1,
               const float* __restrict__ bias1, void* C10, void* C11,
               int Nt1, int Ms1) {
  __shared__ ushort_t lds[8192];  // 16 KB: data tile [0,4096), W tile [4096,8192)
  const int tid = threadIdx.x;
  const int l = tid & 63, w = tid >> 6;

  // bijective XCD swizzle (all grids here are multiples of 8)
  const int nwg = gridDim.x;
  int id = (blockIdx.x & 7) * (nwg >> 3) + (blockIdx.x >> 3);

  const ushort_t* A; const ushort_t* W; const float* bias;
  void *Cp0, *Cp1, *Cp2; int Ntiles, MbShift;
  if (id < tiles0) {
    A = A0; W = W0; bias = bias0; Cp0 = C00; Cp1 = C01; Cp2 = C02;
    Ntiles = Nt0; MbShift = Ms0;
  } else {
    id -= tiles0;
    A = A1; W = W1; bias = bias1; Cp0 = C10; Cp1 = C11; Cp2 = nullptr;
    Ntiles = Nt1; MbShift = Ms1;
  }
  const int nt = id % Ntiles, mt = id / Ntiles;
  const int bm = mt * 128, bn = nt * 128;

  // staging: thread handles chunks ci = j*256 + w*64 + l (16 B each), j=0..3
  const ushort_t* gsrc[4];
  ushort_t* ldst[4];
#pragma unroll
  for (int j = 0; j < 4; j++) {
    const int ci = j * 256 + w * 64 + l;
    const int row = (ci & 511) >> 2;
    const int cp = (ci & 3) ^ ((row >> 1) & 3);  // pre-swizzled source chunk
    gsrc[j] = (ci < 512 ? A + (size_t)(bm + row) * 512
                        : W + (size_t)(bn + row) * 512) + cp * 8;
    ldst[j] = &lds[j * 2048 + w * 512];  // wave-uniform dest; HW adds lane*16B
  }

  const int wm = (w & 1) * 64, wn = (w >> 1) * 64;
  int boff[4], aoff[4];
#pragma unroll
  for (int i = 0; i < 4; i++) {
    const int rb = wm + i * 16 + (l & 15);
    boff[i] = rb * 32 + (((l >> 4) ^ ((rb >> 1) & 3)) * 8);
    const int ra = wn + i * 16 + (l & 15);
    aoff[i] = 4096 + ra * 32 + (((l >> 4) ^ ((ra >> 1) & 3)) * 8);
  }

  f32x4 acc[4][4] = {};
  for (int kt = 0; kt < 16; kt++) {
    if (kt) __syncthreads();
#pragma unroll
    for (int j = 0; j < 4; j++) gload16(gsrc[j] + kt * 32, ldst[j]);
    __syncthreads();
    bf16x8 bf[4], af[4];
#pragma unroll
    for (int i = 0; i < 4; i++) bf[i] = *(const bf16x8*)&lds[boff[i]];
#pragma unroll
    for (int i = 0; i < 4; i++) af[i] = *(const bf16x8*)&lds[aoff[i]];
#pragma unroll
    for (int ni = 0; ni < 4; ni++)
#pragma unroll
      for (int mi = 0; mi < 4; mi++)
        acc[ni][mi] = __builtin_amdgcn_mfma_f32_16x16x32_bf16(af[ni], bf[mi],
                                                              acc[ni][mi], 0, 0, 0);
  }

  // epilogue: D lane map col(m)=l&15, row(n)=(l>>4)*4+r  [m89-verified]
  const int bufi = bn >> 9;
  void* Cb = bufi == 0 ? Cp0 : (bufi == 1 ? Cp1 : Cp2);
  const int nb = bn & 511;
#pragma unroll
  for (int ni = 0; ni < 4; ni++) {
#pragma unroll
    for (int r = 0; r < 4; r++) {
      const int tn = wn + ni * 16 + (l >> 4) * 4 + r;
      const float bv = bias[bn + tn];
      const int nl = nb + tn;
#pragma unroll
      for (int mi = 0; mi < 4; mi++) {
        const int m = bm + wm + mi * 16 + (l & 15);
        const int b = m >> MbShift, ml = m & ((1 << MbShift) - 1);
        const size_t idx = (((size_t)b * 512 + nl) << MbShift) + ml;
        const float val = acc[ni][mi][r] + bv;
        if (OUTF) ((float*)Cb)[idx] = val;
        else      ((ushort_t*)Cb)[idx] = f2bf(val);
      }
    }
  }
}

// ---------------------------------------------------------------------------
// Fused window attention (verbatim R5 — verified, bf16 out).
//   q/k/v/att: [B][512][L] bf16; ak/av: [BCH][512][AL*L] bf16 (local bb).
// ---------------------------------------------------------------------------
__global__ __launch_bounds__(256)
void attn_win(const ushort_t* __restrict__ q, const ushort_t* __restrict__ k,
              const ushort_t* __restrict__ v, const ushort_t* __restrict__ ak,
              const ushort_t* __restrict__ av, ushort_t* __restrict__ att,
              int b0) {
  const int lane = threadIdx.x & 63;
  const int w    = threadIdx.x >> 6;
  const int dc   = lane & 3;
  const int lc   = lane >> 2;
  const int bb = blockIdx.y >> 3, n = blockIdx.y & 7;
  const int b = b0 + bb;
  const int l8 = blockIdx.x * 512 + w * 128 + lc * 8;
  const int d0 = dc * 16;

  const size_t rq = ((size_t)b * D_ + n * HDIM_ + d0) * L_ + l8;
  const size_t ra = ((size_t)bb * D_ + n * HDIM_ + d0) * (size_t)(AL_ * L_) + l8;
  const ushort_t* qp = q + rq;
  const ushort_t* kp = k + rq;
  const ushort_t* vp = v + rq;
  ushort_t*       op = att + rq;
  const ushort_t* akp = ak + ra;
  const ushort_t* avp = av + ra;

  float s0[8] = {}, s1[8] = {}, s2[8] = {}, s3[8] = {};
  float s4[8] = {}, s5[8] = {}, s6[8] = {};

#pragma unroll 4
  for (int i = 0; i < 16; ++i) {
    const ushort_t* kr = kp + (size_t)i * L_;
    const ushort_t* ar = akp + (size_t)i * (AL_ * L_);
    const u16x8 qv = *(const u16x8*)(qp + (size_t)i * L_);
    const u16x8 kv = *(const u16x8*)kr;
    const u16x8 a0 = *(const u16x8*)(ar);
    const u16x8 a1 = *(const u16x8*)(ar + L_);
    const u16x8 a2 = *(const u16x8*)(ar + 2 * L_);
    const u16x8 a3 = *(const u16x8*)(ar + 3 * L_);
    float qf[8], kf[8];
#pragma unroll
    for (int j = 0; j < 8; ++j) { qf[j] = bf2f(qv[j]); kf[j] = bf2f(kv[j]); }
    float kl = __shfl_up(kf[7], 4);
    if (lc == 0) kl = (l8 > 0) ? bf2f(kr[-1]) : 0.f;
    float kh = __shfl_down(kf[0], 4);
    if (lc == 15) kh = (l8 + 8 < L_) ? bf2f(kr[8]) : 0.f;
#pragma unroll
    for (int j = 0; j < 8; ++j) {
      s0[j] = fmaf(qf[j], j ? kf[j - 1] : kl, s0[j]);
      s1[j] = fmaf(qf[j], kf[j], s1[j]);
      s2[j] = fmaf(qf[j], j < 7 ? kf[j + 1] : kh, s2[j]);
      s3[j] = fmaf(qf[j], bf2f(a0[j]), s3[j]);
      s4[j] = fmaf(qf[j], bf2f(a1[j]), s4[j]);
      s5[j] = fmaf(qf[j], bf2f(a2[j]), s5[j]);
      s6[j] = fmaf(qf[j], bf2f(a3[j]), s6[j]);
    }
  }

#pragma unroll
  for (int j = 0; j < 8; ++j) {
    s0[j] += __shfl_xor(s0[j], 1); s0[j] += __shfl_xor(s0[j], 2);
    s1[j] += __shfl_xor(s1[j], 1); s1[j] += __shfl_xor(s1[j], 2);
    s2[j] += __shfl_xor(s2[j], 1); s2[j] += __shfl_xor(s2[j], 2);
    s3[j] += __shfl_xor(s3[j], 1); s3[j] += __shfl_xor(s3[j], 2);
    s4[j] += __shfl_xor(s4[j], 1); s4[j] += __shfl_xor(s4[j], 2);
    s5[j] += __shfl_xor(s5[j], 1); s5[j] += __shfl_xor(s5[j], 2);
    s6[j] += __shfl_xor(s6[j], 1); s6[j] += __shfl_xor(s6[j], 2);
  }

#pragma unroll
  for (int j = 0; j < 8; ++j) {
    const float t0 = s0[j] * SCALE_, t1 = s1[j] * SCALE_, t2 = s2[j] * SCALE_;
    const float t3 = s3[j] * SCALE_, t4 = s4[j] * SCALE_, t5 = s5[j] * SCALE_;
    const float t6 = s6[j] * SCALE_;
    const float mx = fmaxf(fmaxf(fmaxf(t0, t1), fmaxf(t2, t3)),
                           fmaxf(fmaxf(t4, t5), t6));
    float e0 = __expf(t0 - mx), e1 = __expf(t1 - mx), e2 = __expf(t2 - mx);
    float e3 = __expf(t3 - mx), e4 = __expf(t4 - mx), e5 = __expf(t5 - mx);
    float e6 = __expf(t6 - mx);
    const float inv = 1.f / (e0 + e1 + e2 + e3 + e4 + e5 + e6);
    s0[j] = e0 * inv; s1[j] = e1 * inv; s2[j] = e2 * inv; s3[j] = e3 * inv;
    s4[j] = e4 * inv; s5[j] = e5 * inv; s6[j] = e6 * inv;
  }

#pragma unroll 4
  for (int i = 0; i < 16; ++i) {
    const ushort_t* vr = vp + (size_t)i * L_;
    const ushort_t* ar = avp + (size_t)i * (AL_ * L_);
    const u16x8 vv = *(const u16x8*)vr;
    const u16x8 a0 = *(const u16x8*)(ar);
    const u16x8 a1 = *(const u16x8*)(ar + L_);
    const u16x8 a2 = *(const u16x8*)(ar + 2 * L_);
    const u16x8 a3 = *(const u16x8*)(ar + 3 * L_);
    float vf[8];
#pragma unroll
    for (int j = 0; j < 8; ++j) vf[j] = bf2f(vv[j]);
    float vl = __shfl_up(vf[7], 4);
    if (lc == 0) vl = (l8 > 0) ? bf2f(vr[-1]) : 0.f;
    float vh = __shfl_down(vf[0], 4);
    if (lc == 15) vh = (l8 + 8 < L_) ? bf2f(vr[8]) : 0.f;
    u16x8 o;
#pragma unroll
    for (int j = 0; j < 8; ++j) {
      float r = s0[j] * (j ? vf[j - 1] : vl)
              + s1[j] * vf[j]
              + s2[j] * (j < 7 ? vf[j + 1] : vh);
      r = fmaf(s3[j], bf2f(a0[j]), r);
      r = fmaf(s4[j], bf2f(a1[j]), r);
      r = fmaf(s5[j], bf2f(a2[j]), r);
      r = fmaf(s6[j], bf2f(a3[j]), r);
      o[j] = f2bf(r);
    }
    *(u16x8*)(op + (size_t)i * L_) = o;
  }
}

// ---------------------------------------------------------------------------
extern "C" void kernel_launch(void* const* d_in, const int* in_sizes, int n_in,
                              void* d_out, int out_size, void* d_ws, size_t ws_size,
                              hipStream_t stream) {
  const float* x  = (const float*)d_in[0];
  const float* ax = (const float*)d_in[1];
  const float* Wq = (const float*)d_in[2];
  const float* bq = (const float*)d_in[3];
  const float* Wk = (const float*)d_in[4];
  const float* bk = (const float*)d_in[5];
  const float* Wv = (const float*)d_in[6];
  const float* bv = (const float*)d_in[7];
  const float* Wo = (const float*)d_in[8];
  const float* bo = (const float*)d_in[9];
  float* out = (float*)d_out;

  // ---- workspace layout (bf16 elems) — identical to the proven R4 plan ----
  const size_t E  = (size_t)B_ * D_ * L_;         // 8,388,608
  const size_t EA = (size_t)B_ * D_ * AL_ * L_;   // 33,554,432
  const size_t CH1 = (size_t)D_ * AL_ * L_;       // per-batch ak/av elems
  const size_t wfix = 1536 * 512 + 512 * 512 + 3072;

  int BCH = 8;
  while (BCH > 1 &&
         (4 * E + EA + 2 * (size_t)BCH * CH1 + wfix) * 2 > ws_size)
    BCH >>= 1;
  const size_t chunkE = (size_t)BCH * CH1;

  ushort_t* wsu = (ushort_t*)d_ws;
  ushort_t* xTb   = wsu;              // [B*L][512]   (reused as attb after qkv)
  ushort_t* qb    = xTb + E;          // [B][512][L]
  ushort_t* kb    = qb + E;
  ushort_t* vb    = kb + E;
  ushort_t* axTb  = vb + E;           // [B*AL*L][512] (reused as attTb at end)
  ushort_t* akb   = axTb + EA;        // [BCH][512][AL*L]
  ushort_t* avb   = akb + chunkE;
  ushort_t* WcatT = avb + chunkE;     // [1536][512]
  ushort_t* WoT   = WcatT + 1536 * 512;
  float*    bcat  = (float*)(WoT + 512 * 512);  // [1536]
  ushort_t* attb  = xTb;              // xTb dead after qkv GEMM
  ushort_t* attTb = axTb;             // axTb dead after last akav GEMM

  // 1) weight prep (1 launch)
  wprep<<<dim3(1025), dim3(32, 8), 0, stream>>>(Wq, Wk, Wv, Wo, bq, bk, bv,
                                                WcatT, WoT, bcat);

  // 2) fused x + ax transpose (1 launch, vectorized)
  trans64_in<<<dim3(2048 + 8192), dim3(256), 0, stream>>>(x, xTb, ax, axTb);

  if (BCH == 8) {
    // 3) qkv + akav as ONE GEMM dispatch: 1536 + 4096 tiles
    gemm_dual<0><<<dim3(1536 + 4096), dim3(256), 0, stream>>>(
        xTb, WcatT, bcat, qb, kb, vb, 12, 11, 1536,
        axTb, WcatT + 512 * 512, bcat + 512, akb, avb, 8, 13);
    // 4) attention (1 launch)
    attn_win<<<dim3(L_ / 512, B_ * NHEAD_), dim3(256), 0, stream>>>(
        qb, kb, vb, akb, avb, attb, 0);
  } else {
    // fallback: chunked akav (ws-limited), qkv first
    gemm_dual<0><<<dim3(1536), dim3(256), 0, stream>>>(
        xTb, WcatT, bcat, qb, kb, vb, 12, 11, 1536,
        xTb, WcatT, bcat, qb, kb, 12, 11);
    for (int b0 = 0; b0 < B_; b0 += BCH) {
      const ushort_t* axc = axTb + (size_t)b0 * CH1;
      gemm_dual<0><<<dim3(BCH * 512), dim3(256), 0, stream>>>(
          axc, WcatT + 512 * 512, bcat + 512, akb, avb, nullptr, 8, 13, 0,
          axc, WcatT + 512 * 512, bcat + 512, akb, avb, 8, 13);
      attn_win<<<dim3(L_ / 512, BCH * NHEAD_), dim3(256), 0, stream>>>(
          qb, kb, vb, akb, avb, attb, b0);
    }
  }

  // 5) att -> attT (1 launch, vectorized; overwrites axTb — all readers done)
  trans64_bf<<<dim3(2048), dim3(256), 0, stream>>>(attb, attTb);

  // 6) output projection (fp32 out), single-problem via tiles0 = grid
  gemm_dual<1><<<dim3(512), dim3(256), 0, stream>>>(
      attTb, WoT, bo, out, nullptr, nullptr, 4, 11, 512,
      attTb, WoT, bo, out, nullptr, 4, 11);
}

// Round 10
// 469.655 us; speedup vs baseline: 1.2017x; 1.0192x over previous
//
#include <hip/hip_runtime.h>
#include <hip/hip_bf16.h>

// Problem constants (fixed by the reference)
#define B_ 8
#define NHID_ 512
#define L_ 2048
#define AL_ 4
#define NHEAD_ 8
#define HDIM_ 64
#define D_ 512
#define SCALE_ 0.125f

typedef unsigned short ushort_t;
typedef __attribute__((ext_vector_type(8))) short bf16x8;
typedef __attribute__((ext_vector_type(8))) unsigned short u16x8;
typedef __attribute__((ext_vector_type(4))) unsigned short u16x4;
typedef __attribute__((ext_vector_type(4))) float f32x4;

__device__ __forceinline__ float bf2f(ushort_t u) {
  union { unsigned i; float f; } x; x.i = ((unsigned)u) << 16; return x.f;
}
__device__ __forceinline__ ushort_t f2bf(float f) {   // round-to-nearest-even
  unsigned u = __float_as_uint(f);
  unsigned r = (u + 0x7FFFu + ((u >> 16) & 1u)) >> 16;
  return (ushort_t)r;
}
__device__ __forceinline__ void gload16(const ushort_t* g, ushort_t* l) {
  __builtin_amdgcn_global_load_lds(
      (const __attribute__((address_space(1))) unsigned int*)g,
      (__attribute__((address_space(3))) unsigned int*)l, 16, 0, 0);
}

// ---------------------------------------------------------------------------
// Fused weight prep (ONE launch) — unchanged from R9 (verified).
// ---------------------------------------------------------------------------
__global__ __launch_bounds__(256)
void wprep(const float* __restrict__ Wq, const float* __restrict__ Wk,
           const float* __restrict__ Wv, const float* __restrict__ Wo,
           const float* __restrict__ bq, const float* __restrict__ bk,
           const float* __restrict__ bv, ushort_t* __restrict__ WcatT,
           ushort_t* __restrict__ WoT, float* __restrict__ bcat) {
  const int bid = blockIdx.x;
  const int tx = threadIdx.x, ty = threadIdx.y;
  if (bid == 1024) {  // bias concat
    const int t = ty * 32 + tx;
    for (int i = t; i < 1536; i += 256) {
      const float* s = i < 512 ? bq : (i < 1024 ? bk : bv);
      bcat[i] = s[i & 511];
    }
    return;
  }
  __shared__ float tl[32][33];
  const int wi = bid >> 8;  // 0..3
  const float* src = wi == 0 ? Wq : wi == 1 ? Wk : wi == 2 ? Wv : Wo;
  ushort_t* dst = wi == 0 ? WcatT : wi == 1 ? WcatT + 512 * 512
                : wi == 2 ? WcatT + 1024 * 512 : WoT;
  const int r = bid & 255;
  const int cb = (r & 15) * 32, rb = (r >> 4) * 32;
#pragma unroll
  for (int i = 0; i < 4; i++)
    tl[ty + i * 8][tx] = src[(size_t)(rb + ty + i * 8) * 512 + cb + tx];
  __syncthreads();
#pragma unroll
  for (int i = 0; i < 4; i++)
    dst[(size_t)(cb + ty + i * 8) * 512 + rb + tx] = f2bf(tl[tx][ty + i * 8]);
}

// ---------------------------------------------------------------------------
// Vectorized 64x64 transpose+convert — unchanged from R9 (verified).
// ---------------------------------------------------------------------------
__global__ __launch_bounds__(256)
void trans64_in(const float* __restrict__ x, ushort_t* __restrict__ xT,
                const float* __restrict__ ax, ushort_t* __restrict__ axT) {
  __shared__ ushort_t tl[64][68];
  int id = blockIdx.x;
  const float* in; ushort_t* out; int C, z, rt, ct;
  if (id < 2048) {            // x: 8 z * (8 rt * 32 ct)
    in = x; out = xT; C = 2048;
    z = id >> 8; const int r = id & 255; ct = r & 31; rt = r >> 5;
  } else {                    // ax: 8 z * (8 rt * 128 ct)
    id -= 2048;
    in = ax; out = axT; C = 8192;
    z = id >> 10; const int r = id & 1023; ct = r & 127; rt = r >> 7;
  }
  const int rb = rt * 64, cb = ct * 64;
  const int t = threadIdx.x;
  const int cx = t & 15, ry = t >> 4;
#pragma unroll
  for (int i = 0; i < 4; i++) {
    const int rl = ry + i * 16;
    const float4 v = *(const float4*)&in[((size_t)z * 512 + rb + rl) * C + cb + cx * 4];
    u16x4 u; u[0] = f2bf(v.x); u[1] = f2bf(v.y); u[2] = f2bf(v.z); u[3] = f2bf(v.w);
    *(u16x4*)&tl[rl][cx * 4] = u;
  }
  __syncthreads();
  const int rx = t & 15, cy = t >> 4;
#pragma unroll
  for (int i = 0; i < 4; i++) {
    const int cl = cy + i * 16;
    u16x4 u;
#pragma unroll
    for (int j = 0; j < 4; j++) u[j] = tl[rx * 4 + j][cl];
    *(u16x4*)&out[((size_t)z * C + cb + cl) * 512 + rb + rx * 4] = u;
  }
}

// Same 64x64 transpose for bf16 input (att -> attT) — unchanged from R9.
__global__ __launch_bounds__(256)
void trans64_bf(const ushort_t* __restrict__ in, ushort_t* __restrict__ out) {
  __shared__ ushort_t tl[64][68];
  const int id = blockIdx.x;           // 8 z * (8 rt * 32 ct) = 2048
  const int z = id >> 8; const int r = id & 255;
  const int ct = r & 31, rt = r >> 5;
  const int rb = rt * 64, cb = ct * 64;
  const int t = threadIdx.x;
  const int cx = t & 15, ry = t >> 4;
#pragma unroll
  for (int i = 0; i < 4; i++) {
    const int rl = ry + i * 16;
    const u16x4 v = *(const u16x4*)&in[((size_t)z * 512 + rb + rl) * 2048 + cb + cx * 4];
    *(u16x4*)&tl[rl][cx * 4] = v;
  }
  __syncthreads();
  const int rx = t & 15, cy = t >> 4;
#pragma unroll
  for (int i = 0; i < 4; i++) {
    const int cl = cy + i * 16;
    u16x4 u;
#pragma unroll
    for (int j = 0; j < 4; j++) u[j] = tl[rx * 4 + j][cl];
    *(u16x4*)&out[((size_t)z * 2048 + cb + cl) * 512 + rb + rx * 4] = u;
  }
}

// ---------------------------------------------------------------------------
// bf16 MFMA GEMM, DUAL-problem dispatch. NEW this round: 3-buffer counted-
// vmcnt pipeline (T4) — STAGE for k-steps kt+1/kt+2 stays in flight across
// RAW s_barriers; steady-state wait is vmcnt(4), never vmcnt(0).
// Layouts/swizzle/epilogue identical to the R5/R9-verified kernel:
//   C[b][n][m] = sum_k A[(b,m)][k] * Wt[n][k] + bias[n]
//   Tile 128x128, BK=32, 4 waves, 4x4 16x16x32 frags; gload_lds(16B);
//   XOR chunk swizzle c^((row>>1)&3) both sides (rule #21).
// Buffer safety: buf written at iter kt (for kt+2) was last ds_read at iter
// kt-1 and fully consumed (MFMA reg dependence) before that iter's closing
// barrier — no alias race. VMEM returns are in-order (vmcnt semantics).
// ---------------------------------------------------------------------------
template <int OUTF>
__global__ __launch_bounds__(256)
void gemm_dual(const ushort_t* __restrict__ A0, const ushort_t* __restrict__ W0,
               const float* __restrict__ bias0, void* C00, void* C01, void* C02,
               int Nt0, int Ms0, int tiles0,
               const ushort_t* __restrict__ A1, const ushort_t* __restrict__ W1,
               const float* __restrict__ bias1, void* C10, void* C11,
               int Nt1, int Ms1) {
  __shared__ ushort_t lds[24576];  // 48 KB: 3 k-step buffers x (A 4096 | W 4096)
  const int tid = threadIdx.x;
  const int l = tid & 63, w = tid >> 6;

  // bijective XCD swizzle (all grids here are multiples of 8)
  const int nwg = gridDim.x;
  int id = (blockIdx.x & 7) * (nwg >> 3) + (blockIdx.x >> 3);

  const ushort_t* A; const ushort_t* W; const float* bias;
  void *Cp0, *Cp1, *Cp2; int Ntiles, MbShift;
  if (id < tiles0) {
    A = A0; W = W0; bias = bias0; Cp0 = C00; Cp1 = C01; Cp2 = C02;
    Ntiles = Nt0; MbShift = Ms0;
  } else {
    id -= tiles0;
    A = A1; W = W1; bias = bias1; Cp0 = C10; Cp1 = C11; Cp2 = nullptr;
    Ntiles = Nt1; MbShift = Ms1;
  }
  const int nt = id % Ntiles, mt = id / Ntiles;
  const int bm = mt * 128, bn = nt * 128;

  // staging: thread handles chunks ci = j*256 + w*64 + l (16 B each), j=0..3
  const ushort_t* gsrc[4];
  int ldoff[4];
#pragma unroll
  for (int j = 0; j < 4; j++) {
    const int ci = j * 256 + w * 64 + l;
    const int row = (ci & 511) >> 2;
    const int cp = (ci & 3) ^ ((row >> 1) & 3);  // pre-swizzled source chunk
    gsrc[j] = (ci < 512 ? A + (size_t)(bm + row) * 512
                        : W + (size_t)(bn + row) * 512) + cp * 8;
    ldoff[j] = j * 2048 + w * 512;  // wave-uniform dest; HW adds lane*16B
  }

  const int wm = (w & 1) * 64, wn = (w >> 1) * 64;
  int boff[4], aoff[4];
#pragma unroll
  for (int i = 0; i < 4; i++) {
    const int rb = wm + i * 16 + (l & 15);
    boff[i] = rb * 32 + (((l >> 4) ^ ((rb >> 1) & 3)) * 8);
    const int ra = wn + i * 16 + (l & 15);
    aoff[i] = 4096 + ra * 32 + (((l >> 4) ^ ((ra >> 1) & 3)) * 8);
  }

#define STAGE(buf, kt)                                                    \
  {                                                                       \
    _Pragma("unroll") for (int j = 0; j < 4; j++)                         \
        gload16(gsrc[j] + (kt) * 32, &lds[(buf) * 8192 + ldoff[j]]);      \
  }

  f32x4 acc[4][4] = {};
  // prologue: 8 VMEM in flight (k-steps 0 and 1)
  STAGE(0, 0);
  STAGE(1, 1);

#pragma unroll
  for (int kt = 0; kt < 16; kt++) {
    const int rb3 = kt % 3;                 // compile-time under full unroll
    if (kt < 15)
      asm volatile("s_waitcnt vmcnt(4)" ::: "memory");  // kt's 4 landed
    else
      asm volatile("s_waitcnt vmcnt(0)" ::: "memory");  // last step: drain
    asm volatile("s_barrier" ::: "memory"); // all waves' chunks of buf ready
    const int base = rb3 * 8192;
    bf16x8 bf[4], af[4];
#pragma unroll
    for (int i = 0; i < 4; i++) bf[i] = *(const bf16x8*)&lds[base + boff[i]];
#pragma unroll
    for (int i = 0; i < 4; i++) af[i] = *(const bf16x8*)&lds[base + aoff[i]];
    if (kt + 2 < 16) STAGE((kt + 2) % 3, kt + 2);  // keep pipe 2-deep
#pragma unroll
    for (int ni = 0; ni < 4; ni++)
#pragma unroll
      for (int mi = 0; mi < 4; mi++)
        acc[ni][mi] = __builtin_amdgcn_mfma_f32_16x16x32_bf16(af[ni], bf[mi],
                                                              acc[ni][mi], 0, 0, 0);
    asm volatile("s_barrier" ::: "memory"); // buf consumed by all waves
  }
#undef STAGE

  // epilogue: D lane map col(m)=l&15, row(n)=(l>>4)*4+r  [m89-verified]
  const int bufi = bn >> 9;
  void* Cb = bufi == 0 ? Cp0 : (bufi == 1 ? Cp1 : Cp2);
  const int nb = bn & 511;
#pragma unroll
  for (int ni = 0; ni < 4; ni++) {
#pragma unroll
    for (int r = 0; r < 4; r++) {
      const int tn = wn + ni * 16 + (l >> 4) * 4 + r;
      const float bv = bias[bn + tn];
      const int nl = nb + tn;
#pragma unroll
      for (int mi = 0; mi < 4; mi++) {
        const int m = bm + wm + mi * 16 + (l & 15);
        const int b = m >> MbShift, ml = m & ((1 << MbShift) - 1);
        const size_t idx = (((size_t)b * 512 + nl) << MbShift) + ml;
        const float val = acc[ni][mi][r] + bv;
        if (OUTF) ((float*)Cb)[idx] = val;
        else      ((ushort_t*)Cb)[idx] = f2bf(val);
      }
    }
  }
}

// ---------------------------------------------------------------------------
// Fused window attention (verbatim R5/R9 — verified, bf16 out).
// ---------------------------------------------------------------------------
__global__ __launch_bounds__(256)
void attn_win(const ushort_t* __restrict__ q, const ushort_t* __restrict__ k,
              const ushort_t* __restrict__ v, const ushort_t* __restrict__ ak,
              const ushort_t* __restrict__ av, ushort_t* __restrict__ att,
              int b0) {
  const int lane = threadIdx.x & 63;
  const int w    = threadIdx.x >> 6;
  const int dc   = lane & 3;
  const int lc   = lane >> 2;
  const int bb = blockIdx.y >> 3, n = blockIdx.y & 7;
  const int b = b0 + bb;
  const int l8 = blockIdx.x * 512 + w * 128 + lc * 8;
  const int d0 = dc * 16;

  const size_t rq = ((size_t)b * D_ + n * HDIM_ + d0) * L_ + l8;
  const size_t ra = ((size_t)bb * D_ + n * HDIM_ + d0) * (size_t)(AL_ * L_) + l8;
  const ushort_t* qp = q + rq;
  const ushort_t* kp = k + rq;
  const ushort_t* vp = v + rq;
  ushort_t*       op = att + rq;
  const ushort_t* akp = ak + ra;
  const ushort_t* avp = av + ra;

  float s0[8] = {}, s1[8] = {}, s2[8] = {}, s3[8] = {};
  float s4[8] = {}, s5[8] = {}, s6[8] = {};

#pragma unroll 4
  for (int i = 0; i < 16; ++i) {
    const ushort_t* kr = kp + (size_t)i * L_;
    const ushort_t* ar = akp + (size_t)i * (AL_ * L_);
    const u16x8 qv = *(const u16x8*)(qp + (size_t)i * L_);
    const u16x8 kv = *(const u16x8*)kr;
    const u16x8 a0 = *(const u16x8*)(ar);
    const u16x8 a1 = *(const u16x8*)(ar + L_);
    const u16x8 a2 = *(const u16x8*)(ar + 2 * L_);
    const u16x8 a3 = *(const u16x8*)(ar + 3 * L_);
    float qf[8], kf[8];
#pragma unroll
    for (int j = 0; j < 8; ++j) { qf[j] = bf2f(qv[j]); kf[j] = bf2f(kv[j]); }
    float kl = __shfl_up(kf[7], 4);
    if (lc == 0) kl = (l8 > 0) ? bf2f(kr[-1]) : 0.f;
    float kh = __shfl_down(kf[0], 4);
    if (lc == 15) kh = (l8 + 8 < L_) ? bf2f(kr[8]) : 0.f;
#pragma unroll
    for (int j = 0; j < 8; ++j) {
      s0[j] = fmaf(qf[j], j ? kf[j - 1] : kl, s0[j]);
      s1[j] = fmaf(qf[j], kf[j], s1[j]);
      s2[j] = fmaf(qf[j], j < 7 ? kf[j + 1] : kh, s2[j]);
      s3[j] = fmaf(qf[j], bf2f(a0[j]), s3[j]);
      s4[j] = fmaf(qf[j], bf2f(a1[j]), s4[j]);
      s5[j] = fmaf(qf[j], bf2f(a2[j]), s5[j]);
      s6[j] = fmaf(qf[j], bf2f(a3[j]), s6[j]);
    }
  }

#pragma unroll
  for (int j = 0; j < 8; ++j) {
    s0[j] += __shfl_xor(s0[j], 1); s0[j] += __shfl_xor(s0[j], 2);
    s1[j] += __shfl_xor(s1[j], 1); s1[j] += __shfl_xor(s1[j], 2);
    s2[j] += __shfl_xor(s2[j], 1); s2[j] += __shfl_xor(s2[j], 2);
    s3[j] += __shfl_xor(s3[j], 1); s3[j] += __shfl_xor(s3[j], 2);
    s4[j] += __shfl_xor(s4[j], 1); s4[j] += __shfl_xor(s4[j], 2);
    s5[j] += __shfl_xor(s5[j], 1); s5[j] += __shfl_xor(s5[j], 2);
    s6[j] += __shfl_xor(s6[j], 1); s6[j] += __shfl_xor(s6[j], 2);
  }

#pragma unroll
  for (int j = 0; j < 8; ++j) {
    const float t0 = s0[j] * SCALE_, t1 = s1[j] * SCALE_, t2 = s2[j] * SCALE_;
    const float t3 = s3[j] * SCALE_, t4 = s4[j] * SCALE_, t5 = s5[j] * SCALE_;
    const float t6 = s6[j] * SCALE_;
    const float mx = fmaxf(fmaxf(fmaxf(t0, t1), fmaxf(t2, t3)),
                           fmaxf(fmaxf(t4, t5), t6));
    float e0 = __expf(t0 - mx), e1 = __expf(t1 - mx), e2 = __expf(t2 - mx);
    float e3 = __expf(t3 - mx), e4 = __expf(t4 - mx), e5 = __expf(t5 - mx);
    float e6 = __expf(t6 - mx);
    const float inv = 1.f / (e0 + e1 + e2 + e3 + e4 + e5 + e6);
    s0[j] = e0 * inv; s1[j] = e1 * inv; s2[j] = e2 * inv; s3[j] = e3 * inv;
    s4[j] = e4 * inv; s5[j] = e5 * inv; s6[j] = e6 * inv;
  }

#pragma unroll 4
  for (int i = 0; i < 16; ++i) {
    const ushort_t* vr = vp + (size_t)i * L_;
    const ushort_t* ar = avp + (size_t)i * (AL_ * L_);
    const u16x8 vv = *(const u16x8*)vr;
    const u16x8 a0 = *(const u16x8*)(ar);
    const u16x8 a1 = *(const u16x8*)(ar + L_);
    const u16x8 a2 = *(const u16x8*)(ar + 2 * L_);
    const u16x8 a3 = *(const u16x8*)(ar + 3 * L_);
    float vf[8];
#pragma unroll
    for (int j = 0; j < 8; ++j) vf[j] = bf2f(vv[j]);
    float vl = __shfl_up(vf[7], 4);
    if (lc == 0) vl = (l8 > 0) ? bf2f(vr[-1]) : 0.f;
    float vh = __shfl_down(vf[0], 4);
    if (lc == 15) vh = (l8 + 8 < L_) ? bf2f(vr[8]) : 0.f;
    u16x8 o;
#pragma unroll
    for (int j = 0; j < 8; ++j) {
      float r = s0[j] * (j ? vf[j - 1] : vl)
              + s1[j] * vf[j]
              + s2[j] * (j < 7 ? vf[j + 1] : vh);
      r = fmaf(s3[j], bf2f(a0[j]), r);
      r = fmaf(s4[j], bf2f(a1[j]), r);
      r = fmaf(s5[j], bf2f(a2[j]), r);
      r = fmaf(s6[j], bf2f(a3[j]), r);
      o[j] = f2bf(r);
    }
    *(u16x8*)(op + (size_t)i * L_) = o;
  }
}

// ---------------------------------------------------------------------------
extern "C" void kernel_launch(void* const* d_in, const int* in_sizes, int n_in,
                              void* d_out, int out_size, void* d_ws, size_t ws_size,
                              hipStream_t stream) {
  const float* x  = (const float*)d_in[0];
  const float* ax = (const float*)d_in[1];
  const float* Wq = (const float*)d_in[2];
  const float* bq = (const float*)d_in[3];
  const float* Wk = (const float*)d_in[4];
  const float* bk = (const float*)d_in[5];
  const float* Wv = (const float*)d_in[6];
  const float* bv = (const float*)d_in[7];
  const float* Wo = (const float*)d_in[8];
  const float* bo = (const float*)d_in[9];
  float* out = (float*)d_out;

  // ---- workspace layout (bf16 elems) — identical to the proven R9 plan ----
  const size_t E  = (size_t)B_ * D_ * L_;         // 8,388,608
  const size_t EA = (size_t)B_ * D_ * AL_ * L_;   // 33,554,432
  const size_t CH1 = (size_t)D_ * AL_ * L_;       // per-batch ak/av elems
  const size_t wfix = 1536 * 512 + 512 * 512 + 3072;

  int BCH = 8;
  while (BCH > 1 &&
         (4 * E + EA + 2 * (size_t)BCH * CH1 + wfix) * 2 > ws_size)
    BCH >>= 1;
  const size_t chunkE = (size_t)BCH * CH1;

  ushort_t* wsu = (ushort_t*)d_ws;
  ushort_t* xTb   = wsu;              // [B*L][512]   (reused as attb after qkv)
  ushort_t* qb    = xTb + E;          // [B][512][L]
  ushort_t* kb    = qb + E;
  ushort_t* vb    = kb + E;
  ushort_t* axTb  = vb + E;           // [B*AL*L][512] (reused as attTb at end)
  ushort_t* akb   = axTb + EA;        // [BCH][512][AL*L]
  ushort_t* avb   = akb + chunkE;
  ushort_t* WcatT = avb + chunkE;     // [1536][512]
  ushort_t* WoT   = WcatT + 1536 * 512;
  float*    bcat  = (float*)(WoT + 512 * 512);  // [1536]
  ushort_t* attb  = xTb;              // xTb dead after qkv GEMM
  ushort_t* attTb = axTb;             // axTb dead after last akav GEMM

  // 1) weight prep (1 launch)
  wprep<<<dim3(1025), dim3(32, 8), 0, stream>>>(Wq, Wk, Wv, Wo, bq, bk, bv,
                                                WcatT, WoT, bcat);

  // 2) fused x + ax transpose (1 launch, vectorized)
  trans64_in<<<dim3(2048 + 8192), dim3(256), 0, stream>>>(x, xTb, ax, axTb);

  if (BCH == 8) {
    // 3) qkv + akav as ONE GEMM dispatch: 1536 + 4096 tiles
    gemm_dual<0><<<dim3(1536 + 4096), dim3(256), 0, stream>>>(
        xTb, WcatT, bcat, qb, kb, vb, 12, 11, 1536,
        axTb, WcatT + 512 * 512, bcat + 512, akb, avb, 8, 13);
    // 4) attention (1 launch)
    attn_win<<<dim3(L_ / 512, B_ * NHEAD_), dim3(256), 0, stream>>>(
        qb, kb, vb, akb, avb, attb, 0);
  } else {
    // fallback: chunked akav (ws-limited), qkv first
    gemm_dual<0><<<dim3(1536), dim3(256), 0, stream>>>(
        xTb, WcatT, bcat, qb, kb, vb, 12, 11, 1536,
        xTb, WcatT, bcat, qb, kb, 12, 11);
    for (int b0 = 0; b0 < B_; b0 += BCH) {
      const ushort_t* axc = axTb + (size_t)b0 * CH1;
      gemm_dual<0><<<dim3(BCH * 512), dim3(256), 0, stream>>>(
          axc, WcatT + 512 * 512, bcat + 512, akb, avb, nullptr, 8, 13, 0,
          axc, WcatT + 512 * 512, bcat + 512, akb, avb, 8, 13);
      attn_win<<<dim3(L_ / 512, BCH * NHEAD_), dim3(256), 0, stream>>>(
          qb, kb, vb, akb, avb, attb, b0);
    }
  }

  // 5) att -> attT (1 launch, vectorized; overwrites axTb — all readers done)
  trans64_bf<<<dim3(2048), dim3(256), 0, stream>>>(attb, attTb);

  // 6) output projection (fp32 out), single-problem via tiles0 = grid
  gemm_dual<1><<<dim3(512), dim3(256), 0, stream>>>(
      attTb, WoT, bo, out, nullptr, nullptr, 4, 11, 512,
      attTb, WoT, bo, out, nullptr, 4, 11);
}